// Round 6
// baseline (18760.997 us; speedup 1.0000x reference)
//
#include <hip/hip_runtime.h>

#define BATCH    16384
#define H_DIM    1024
#define D_DIM    512
#define O_DIM    10
#define SEQ      128
#define BM       64
#define NTHREADS 512
#define LSTR     1032   // bf16 elems per LDS row (2064 B)

typedef __bf16 bf16;
typedef __bf16 bf16x8 __attribute__((ext_vector_type(8)));
typedef float  f32x16 __attribute__((ext_vector_type(16)));
typedef float  f32x4  __attribute__((ext_vector_type(4)));

// ---- static device buffers ----
__device__ bf16  g_x[BATCH * D_DIM];       // 16 MB  (bf16 of x)
__device__ bf16  g_whx[H_DIM * D_DIM];     // 1 MB   (row-major, phase-0 only)
__device__ bf16  g_whhp[H_DIM * H_DIM];    // 2 MB   (wave-fragment-packed Whh; L2-resident)
__device__ bf16  g_wph[O_DIM * H_DIM];     // 20 KB
__device__ float g_bias[H_DIM];            // Whx_b + Whh_b
__device__ float g_bph[O_DIM];

__device__ __forceinline__ float fast_tanh(float z) {
  float e = __expf(2.0f * z);
  return 1.0f - 2.0f / (e + 1.0f);
}

// ---- fp32 -> bf16 (8 elems/thread) ----
__global__ void cvt_bf16(const float* __restrict__ src, bf16* __restrict__ dst, int n) {
  const int i = (blockIdx.x * blockDim.x + threadIdx.x) * 8;
  if (i >= n) return;
  f32x4 s0 = *(const f32x4*)(src + i);
  f32x4 s1 = *(const f32x4*)(src + i + 4);
  bf16x8 v;
  #pragma unroll
  for (int j = 0; j < 4; ++j) { v[j] = (bf16)s0[j]; v[4 + j] = (bf16)s1[j]; }
  *(bf16x8*)(dst + i) = v;
}

// ---- pack Whh into per-wave linear streams ----
// dst[(((w*64+kc)*4+nt)*64+lane)*8+j] = Whh[w*128+nt*32+(lane&31)][kc*16+(lane>>5)*8+j]
__global__ void pack_whh(const float* __restrict__ src, bf16* __restrict__ dst) {
  const int t = blockIdx.x * blockDim.x + threadIdx.x;   // 0..131071
  const int lane = t & 63;
  const int gidx = t >> 6;                 // (w*64+kc)*4+nt
  const int nt = gidx & 3, kc = (gidx >> 2) & 63, w = gidx >> 8;
  const int row = w * 128 + nt * 32 + (lane & 31);
  const int col = kc * 16 + (lane >> 5) * 8;
  const float* s = src + (size_t)row * H_DIM + col;
  bf16x8 v;
  #pragma unroll
  for (int j = 0; j < 8; ++j) v[j] = (bf16)s[j];
  *(bf16x8*)(dst + (size_t)t * 8) = v;
}

__global__ void cvt_bias(const float* __restrict__ bx, const float* __restrict__ bh,
                         const float* __restrict__ bp) {
  const int i = blockIdx.x * blockDim.x + threadIdx.x;
  if (i < H_DIM) g_bias[i] = bx[i] + bh[i];
  if (i < O_DIM) g_bph[i]  = bp[i];
}

#define MFMA8(A0, A1, B)                                                              \
  acc[0][0] = __builtin_amdgcn_mfma_f32_32x32x16_bf16(A0, (B)[0], acc[0][0], 0, 0, 0); \
  acc[0][1] = __builtin_amdgcn_mfma_f32_32x32x16_bf16(A0, (B)[1], acc[0][1], 0, 0, 0); \
  acc[0][2] = __builtin_amdgcn_mfma_f32_32x32x16_bf16(A0, (B)[2], acc[0][2], 0, 0, 0); \
  acc[0][3] = __builtin_amdgcn_mfma_f32_32x32x16_bf16(A0, (B)[3], acc[0][3], 0, 0, 0); \
  acc[1][0] = __builtin_amdgcn_mfma_f32_32x32x16_bf16(A1, (B)[0], acc[1][0], 0, 0, 0); \
  acc[1][1] = __builtin_amdgcn_mfma_f32_32x32x16_bf16(A1, (B)[1], acc[1][1], 0, 0, 0); \
  acc[1][2] = __builtin_amdgcn_mfma_f32_32x32x16_bf16(A1, (B)[2], acc[1][2], 0, 0, 0); \
  acc[1][3] = __builtin_amdgcn_mfma_f32_32x32x16_bf16(A1, (B)[3], acc[1][3], 0, 0, 0);

// One block owns BM=64 batch rows for all 128 steps. 8 waves x (64 rows x 128 cols).
// h in LDS (bf16). Whh: packed per-wave linear stream (L2-resident, coalesced),
// depth-2 register double-buffer. xW+biases: packed bf16 in REGISTERS (r4-style)
// -- no global xW stream, so L2 retains Whh (r5's 22 GB HBM refetch came from
// the 4 MB/XCD/step xW stream thrashing the 4 MB L2).
__global__ __launch_bounds__(NTHREADS, 2)
void rnn_fused(float* __restrict__ out)
{
  extern __shared__ char smem[];
  bf16* hbuf = (bf16*)smem;

  const int tid  = threadIdx.x;
  const int wave = tid >> 6;
  const int lane = tid & 63;
  const int m31  = lane & 31;
  const int q    = lane >> 5;
  const int r0   = blockIdx.x * BM;
  const int nw0  = wave * 128;

  const bf16* bstr = g_whhp + (size_t)wave * (64 * 4 * 512) + lane * 8;

  f32x16 acc[2][4];
  bf16x8 xw[16];                 // loop-invariant xW+biases, acc-fragment order

  // ---------------- Phase 0: xwb = x @ Whx^T + bias; h1 = tanh(xwb) ----------------
  #pragma unroll
  for (int mt = 0; mt < 2; ++mt)
    #pragma unroll
    for (int nt = 0; nt < 4; ++nt)
      #pragma unroll
      for (int i = 0; i < 16; ++i) acc[mt][nt][i] = 0.0f;

  {
    const bf16* aBase = g_x + (size_t)(r0 + m31) * D_DIM + q * 8;
    #pragma unroll 4
    for (int kc = 0; kc < D_DIM / 16; ++kc) {
      bf16x8 a[2], b[4];
      #pragma unroll
      for (int mt = 0; mt < 2; ++mt)
        a[mt] = *(const bf16x8*)(aBase + (size_t)mt * 32 * D_DIM + kc * 16);
      #pragma unroll
      for (int nt = 0; nt < 4; ++nt)
        b[nt] = *(const bf16x8*)(g_whx + (size_t)(nw0 + nt * 32 + m31) * D_DIM + kc * 16 + q * 8);
      MFMA8(a[0], a[1], b);
    }
  }

  #pragma unroll
  for (int nt = 0; nt < 4; ++nt) {
    const int col = nw0 + nt * 32 + m31;
    const float bias = g_bias[col];
    #pragma unroll
    for (int mt = 0; mt < 2; ++mt)
      #pragma unroll
      for (int r = 0; r < 16; ++r) {
        const int row = mt * 32 + (r & 3) + 8 * (r >> 2) + 4 * q;  // C/D layout (m74/m101)
        const int idx = (nt * 2 + mt) * 16 + r;
        const float v = acc[mt][nt][r] + bias;
        xw[idx >> 3][idx & 7] = (bf16)v;
        hbuf[row * LSTR + col] = (bf16)fast_tanh(v);
      }
  }
  __syncthreads();

  // ---------------- RNN steps 2..SEQ ----------------
  const bf16* aP0 = hbuf + m31 * LSTR + q * 8;
  const bf16* aP1 = aP0 + 32 * LSTR;

  for (int step = 1; step < SEQ; ++step) {
    #pragma unroll
    for (int mt = 0; mt < 2; ++mt)
      #pragma unroll
      for (int nt = 0; nt < 4; ++nt)
        #pragma unroll
        for (int i = 0; i < 16; ++i) acc[mt][nt][i] = 0.0f;

    bf16x8 bb[2][4];
    #pragma unroll
    for (int nt = 0; nt < 4; ++nt) bb[0][nt] = *(const bf16x8*)(bstr + nt * 512);
    #pragma unroll
    for (int nt = 0; nt < 4; ++nt) bb[1][nt] = *(const bf16x8*)(bstr + (4 + nt) * 512);

    #pragma unroll
    for (int kc = 0; kc < 64; ++kc) {
      bf16x8 a0 = *(const bf16x8*)(aP0 + kc * 16);
      bf16x8 a1 = *(const bf16x8*)(aP1 + kc * 16);
      MFMA8(a0, a1, bb[kc & 1]);
      if (kc + 2 < 64) {
        #pragma unroll
        for (int nt = 0; nt < 4; ++nt)
          bb[kc & 1][nt] = *(const bf16x8*)(bstr + ((kc + 2) * 4 + nt) * 512);
      }
    }

    __syncthreads();   // all waves done READING hbuf

    #pragma unroll
    for (int nt = 0; nt < 4; ++nt) {
      const int col = nw0 + nt * 32 + m31;
      #pragma unroll
      for (int mt = 0; mt < 2; ++mt)
        #pragma unroll
        for (int r = 0; r < 16; ++r) {
          const int row = mt * 32 + (r & 3) + 8 * (r >> 2) + 4 * q;
          const int idx = (nt * 2 + mt) * 16 + r;
          hbuf[row * LSTR + col] = (bf16)fast_tanh(acc[mt][nt][r] + (float)xw[idx >> 3][idx & 7]);
        }
    }
    __syncthreads();   // new h visible
  }

  // ---------------- Output head: softmax(h @ Wph^T + b), fp32 out ----------------
  {
    const int row  = tid >> 3;
    const int tsub = tid & 7;
    float p[O_DIM];
    #pragma unroll
    for (int o = 0; o < O_DIM; ++o) p[o] = 0.0f;

    const bf16* hrow = hbuf + row * LSTR;
    const int k0 = tsub * 128;
    for (int kk = 0; kk < 128; kk += 8) {
      bf16x8 hv = *(const bf16x8*)(hrow + k0 + kk);
      float hf[8];
      #pragma unroll
      for (int j = 0; j < 8; ++j) hf[j] = (float)hv[j];
      #pragma unroll
      for (int o = 0; o < O_DIM; ++o) {
        bf16x8 wv = *(const bf16x8*)(g_wph + (size_t)o * H_DIM + k0 + kk);
        #pragma unroll
        for (int j = 0; j < 8; ++j) p[o] += hf[j] * (float)wv[j];
      }
    }
    #pragma unroll
    for (int d = 1; d < 8; d <<= 1)
      #pragma unroll
      for (int o = 0; o < O_DIM; ++o) p[o] += __shfl_xor(p[o], d, 8);

    if (tsub == 0) {
      float v[O_DIM], mx = -1e30f;
      #pragma unroll
      for (int o = 0; o < O_DIM; ++o) { v[o] = p[o] + g_bph[o]; mx = fmaxf(mx, v[o]); }
      float s = 0.0f;
      #pragma unroll
      for (int o = 0; o < O_DIM; ++o) { v[o] = __expf(v[o] - mx); s += v[o]; }
      const float inv = 1.0f / s;
      #pragma unroll
      for (int o = 0; o < O_DIM; ++o)
        out[(size_t)(r0 + row) * O_DIM + o] = v[o] * inv;
    }
  }
}

extern "C" void kernel_launch(void* const* d_in, const int* in_sizes, int n_in,
                              void* d_out, int out_size, void* d_ws, size_t ws_size,
                              hipStream_t stream)
{
  (void)d_ws; (void)ws_size; (void)in_sizes; (void)n_in; (void)out_size;
  const float* x     = (const float*)d_in[0];
  const float* Whx_w = (const float*)d_in[1];
  const float* Whx_b = (const float*)d_in[2];
  const float* Whh_w = (const float*)d_in[3];
  const float* Whh_b = (const float*)d_in[4];
  const float* Wph_w = (const float*)d_in[5];
  const float* Wph_b = (const float*)d_in[6];
  float* out = (float*)d_out;

  (void)hipFuncSetAttribute((const void*)rnn_fused,
                            hipFuncAttributeMaxDynamicSharedMemorySize, 132096);

  bf16* gx; bf16* gwhx; bf16* gwhhp; bf16* gwph;
  hipGetSymbolAddress((void**)&gx,    HIP_SYMBOL(g_x));
  hipGetSymbolAddress((void**)&gwhx,  HIP_SYMBOL(g_whx));
  hipGetSymbolAddress((void**)&gwhhp, HIP_SYMBOL(g_whhp));
  hipGetSymbolAddress((void**)&gwph,  HIP_SYMBOL(g_wph));

  cvt_bf16<<<BATCH * D_DIM / 2048, 256, 0, stream>>>(x,     gx,   BATCH * D_DIM);
  cvt_bf16<<<H_DIM * D_DIM / 2048, 256, 0, stream>>>(Whx_w, gwhx, H_DIM * D_DIM);
  pack_whh<<<H_DIM * H_DIM / 8 / 256, 256, 0, stream>>>(Whh_w, gwhhp);
  cvt_bf16<<<(O_DIM * H_DIM / 8 + 255) / 256, 256, 0, stream>>>(Wph_w, gwph, O_DIM * H_DIM);
  cvt_bias<<<4, 256, 0, stream>>>(Whx_b, Whh_b, Wph_b);

  const dim3 grid(BATCH / BM), block(NTHREADS);
  const size_t lds = (size_t)BM * LSTR * sizeof(bf16);   // 132096 B
  rnn_fused<<<grid, block, lds, stream>>>(out);
}

// Round 7
// 18178.702 us; speedup vs baseline: 1.0320x; 1.0320x over previous
//
#include <hip/hip_runtime.h>
#include <hip/hip_cooperative_groups.h>

namespace cg = cooperative_groups;

#define BATCH    16384
#define H_DIM    1024
#define D_DIM    512
#define O_DIM    10
#define SEQ      128
#define BM       64
#define NTHREADS 512
#define LSTR     1032   // bf16 elems per LDS row (2064 B; 4-way on A-reads, ~1.6x LDS pipe, hidden under MFMA)

typedef __bf16 bf16;
typedef __bf16 bf16x8 __attribute__((ext_vector_type(8)));
typedef float  f32x16 __attribute__((ext_vector_type(16)));
typedef float  f32x4  __attribute__((ext_vector_type(4)));

// ---- static device buffers ----
__device__ bf16  g_x[BATCH * D_DIM];       // 16 MB  (bf16 of x)
__device__ bf16  g_whx[H_DIM * D_DIM];     // 1 MB   (row-major, phase-0 only)
__device__ bf16  g_whhp[H_DIM * H_DIM];    // 2 MB   (wave-fragment-packed Whh)
__device__ bf16  g_wph[O_DIM * H_DIM];     // 20 KB
__device__ float g_bias[H_DIM];            // Whx_b + Whh_b
__device__ float g_bph[O_DIM];

__device__ __forceinline__ float fast_tanh(float z) {
  float e = __expf(2.0f * z);
  return 1.0f - 2.0f / (e + 1.0f);
}

// ---- fp32 -> bf16 (8 elems/thread) ----
__global__ void cvt_bf16(const float* __restrict__ src, bf16* __restrict__ dst, int n) {
  const int i = (blockIdx.x * blockDim.x + threadIdx.x) * 8;
  if (i >= n) return;
  f32x4 s0 = *(const f32x4*)(src + i);
  f32x4 s1 = *(const f32x4*)(src + i + 4);
  bf16x8 v;
  #pragma unroll
  for (int j = 0; j < 4; ++j) { v[j] = (bf16)s0[j]; v[4 + j] = (bf16)s1[j]; }
  *(bf16x8*)(dst + i) = v;
}

// ---- pack Whh into per-wave linear streams ----
// dst[(((w*64+kc)*4+nt)*64+lane)*8+j] = Whh[w*128+nt*32+(lane&31)][kc*16+(lane>>5)*8+j]
__global__ void pack_whh(const float* __restrict__ src, bf16* __restrict__ dst) {
  const int t = blockIdx.x * blockDim.x + threadIdx.x;   // 0..131071
  const int lane = t & 63;
  const int gidx = t >> 6;                 // (w*64+kc)*4+nt
  const int nt = gidx & 3, kc = (gidx >> 2) & 63, w = gidx >> 8;
  const int row = w * 128 + nt * 32 + (lane & 31);
  const int col = kc * 16 + (lane >> 5) * 8;
  const float* s = src + (size_t)row * H_DIM + col;
  bf16x8 v;
  #pragma unroll
  for (int j = 0; j < 8; ++j) v[j] = (bf16)s[j];
  *(bf16x8*)(dst + (size_t)t * 8) = v;
}

__global__ void cvt_bias(const float* __restrict__ bx, const float* __restrict__ bh,
                         const float* __restrict__ bp) {
  const int i = blockIdx.x * blockDim.x + threadIdx.x;
  if (i < H_DIM) g_bias[i] = bx[i] + bh[i];
  if (i < O_DIM) g_bph[i]  = bp[i];
}

#define MFMA8(A0, A1, B)                                                              \
  acc[0][0] = __builtin_amdgcn_mfma_f32_32x32x16_bf16(A0, (B)[0], acc[0][0], 0, 0, 0); \
  acc[0][1] = __builtin_amdgcn_mfma_f32_32x32x16_bf16(A0, (B)[1], acc[0][1], 0, 0, 0); \
  acc[0][2] = __builtin_amdgcn_mfma_f32_32x32x16_bf16(A0, (B)[2], acc[0][2], 0, 0, 0); \
  acc[0][3] = __builtin_amdgcn_mfma_f32_32x32x16_bf16(A0, (B)[3], acc[0][3], 0, 0, 0); \
  acc[1][0] = __builtin_amdgcn_mfma_f32_32x32x16_bf16(A1, (B)[0], acc[1][0], 0, 0, 0); \
  acc[1][1] = __builtin_amdgcn_mfma_f32_32x32x16_bf16(A1, (B)[1], acc[1][1], 0, 0, 0); \
  acc[1][2] = __builtin_amdgcn_mfma_f32_32x32x16_bf16(A1, (B)[2], acc[1][2], 0, 0, 0); \
  acc[1][3] = __builtin_amdgcn_mfma_f32_32x32x16_bf16(A1, (B)[3], acc[1][3], 0, 0, 0);

// One block owns BM=64 batch rows for all 128 steps. 8 waves x (64 rows x 128 cols).
// h in LDS. Whh: packed per-wave linear streams (minimal L2 requests).
// xW+biases in registers (no L2 pollution). grid.sync() each step phase-locks
// all 256 blocks so the 32 CUs of an XCD read the shared 2 MB Whh within one
// window -> L2 retains it (r5/r6's 22 GB FETCH = skew-induced L2 misses).
__global__ __launch_bounds__(NTHREADS, 2)
void rnn_fused(float* __restrict__ out)
{
  extern __shared__ char smem[];
  bf16* hbuf = (bf16*)smem;

  const int tid  = threadIdx.x;
  const int wave = tid >> 6;
  const int lane = tid & 63;
  const int m31  = lane & 31;
  const int q    = lane >> 5;
  const int r0   = blockIdx.x * BM;
  const int nw0  = wave * 128;

  const bf16* bstr = g_whhp + (size_t)wave * (64 * 4 * 512) + lane * 8;

  cg::grid_group grid = cg::this_grid();

  f32x16 acc[2][4];
  bf16x8 xw[16];                 // loop-invariant xW+biases, acc-fragment order

  // ---------------- Phase 0: xwb = x @ Whx^T + bias; h1 = tanh(xwb) ----------------
  #pragma unroll
  for (int mt = 0; mt < 2; ++mt)
    #pragma unroll
    for (int nt = 0; nt < 4; ++nt)
      #pragma unroll
      for (int i = 0; i < 16; ++i) acc[mt][nt][i] = 0.0f;

  {
    const bf16* aBase = g_x + (size_t)(r0 + m31) * D_DIM + q * 8;
    #pragma unroll 4
    for (int kc = 0; kc < D_DIM / 16; ++kc) {
      bf16x8 a[2], b[4];
      #pragma unroll
      for (int mt = 0; mt < 2; ++mt)
        a[mt] = *(const bf16x8*)(aBase + (size_t)mt * 32 * D_DIM + kc * 16);
      #pragma unroll
      for (int nt = 0; nt < 4; ++nt)
        b[nt] = *(const bf16x8*)(g_whx + (size_t)(nw0 + nt * 32 + m31) * D_DIM + kc * 16 + q * 8);
      MFMA8(a[0], a[1], b);
    }
  }

  #pragma unroll
  for (int nt = 0; nt < 4; ++nt) {
    const int col = nw0 + nt * 32 + m31;
    const float bias = g_bias[col];
    #pragma unroll
    for (int mt = 0; mt < 2; ++mt)
      #pragma unroll
      for (int r = 0; r < 16; ++r) {
        const int row = mt * 32 + (r & 3) + 8 * (r >> 2) + 4 * q;  // C/D layout (m74/m101)
        const int idx = (nt * 2 + mt) * 16 + r;
        const float v = acc[mt][nt][r] + bias;
        xw[idx >> 3][idx & 7] = (bf16)v;
        hbuf[row * LSTR + col] = (bf16)fast_tanh(v);
      }
  }
  __syncthreads();

  // ---------------- RNN steps 2..SEQ ----------------
  const bf16* aP0 = hbuf + m31 * LSTR + q * 8;
  const bf16* aP1 = aP0 + 32 * LSTR;

  for (int step = 1; step < SEQ; ++step) {
    #pragma unroll
    for (int mt = 0; mt < 2; ++mt)
      #pragma unroll
      for (int nt = 0; nt < 4; ++nt)
        #pragma unroll
        for (int i = 0; i < 16; ++i) acc[mt][nt][i] = 0.0f;

    bf16x8 bb[2][4];
    #pragma unroll
    for (int nt = 0; nt < 4; ++nt) bb[0][nt] = *(const bf16x8*)(bstr + nt * 512);
    #pragma unroll
    for (int nt = 0; nt < 4; ++nt) bb[1][nt] = *(const bf16x8*)(bstr + (4 + nt) * 512);

    #pragma unroll
    for (int kc = 0; kc < 64; ++kc) {
      bf16x8 a0 = *(const bf16x8*)(aP0 + kc * 16);
      bf16x8 a1 = *(const bf16x8*)(aP1 + kc * 16);
      MFMA8(a0, a1, bb[kc & 1]);
      if (kc + 2 < 64) {
        #pragma unroll
        for (int nt = 0; nt < 4; ++nt)
          bb[kc & 1][nt] = *(const bf16x8*)(bstr + ((kc + 2) * 4 + nt) * 512);
      }
    }

    grid.sync();   // phase-lock all blocks; also block-level barrier (hbuf reads done)

    #pragma unroll
    for (int nt = 0; nt < 4; ++nt) {
      const int col = nw0 + nt * 32 + m31;
      #pragma unroll
      for (int mt = 0; mt < 2; ++mt)
        #pragma unroll
        for (int r = 0; r < 16; ++r) {
          const int row = mt * 32 + (r & 3) + 8 * (r >> 2) + 4 * q;
          const int idx = (nt * 2 + mt) * 16 + r;
          hbuf[row * LSTR + col] = (bf16)fast_tanh(acc[mt][nt][r] + (float)xw[idx >> 3][idx & 7]);
        }
    }
    __syncthreads();   // new h visible within block
  }

  // ---------------- Output head: softmax(h @ Wph^T + b), fp32 out ----------------
  {
    const int row  = tid >> 3;
    const int tsub = tid & 7;
    float p[O_DIM];
    #pragma unroll
    for (int o = 0; o < O_DIM; ++o) p[o] = 0.0f;

    const bf16* hrow = hbuf + row * LSTR;
    const int k0 = tsub * 128;
    for (int kk = 0; kk < 128; kk += 8) {
      bf16x8 hv = *(const bf16x8*)(hrow + k0 + kk);
      float hf[8];
      #pragma unroll
      for (int j = 0; j < 8; ++j) hf[j] = (float)hv[j];
      #pragma unroll
      for (int o = 0; o < O_DIM; ++o) {
        bf16x8 wv = *(const bf16x8*)(g_wph + (size_t)o * H_DIM + k0 + kk);
        #pragma unroll
        for (int j = 0; j < 8; ++j) p[o] += hf[j] * (float)wv[j];
      }
    }
    #pragma unroll
    for (int d = 1; d < 8; d <<= 1)
      #pragma unroll
      for (int o = 0; o < O_DIM; ++o) p[o] += __shfl_xor(p[o], d, 8);

    if (tsub == 0) {
      float v[O_DIM], mx = -1e30f;
      #pragma unroll
      for (int o = 0; o < O_DIM; ++o) { v[o] = p[o] + g_bph[o]; mx = fmaxf(mx, v[o]); }
      float s = 0.0f;
      #pragma unroll
      for (int o = 0; o < O_DIM; ++o) { v[o] = __expf(v[o] - mx); s += v[o]; }
      const float inv = 1.0f / s;
      #pragma unroll
      for (int o = 0; o < O_DIM; ++o)
        out[(size_t)(r0 + row) * O_DIM + o] = v[o] * inv;
    }
  }
}

extern "C" void kernel_launch(void* const* d_in, const int* in_sizes, int n_in,
                              void* d_out, int out_size, void* d_ws, size_t ws_size,
                              hipStream_t stream)
{
  (void)d_ws; (void)ws_size; (void)in_sizes; (void)n_in; (void)out_size;
  const float* x     = (const float*)d_in[0];
  const float* Whx_w = (const float*)d_in[1];
  const float* Whx_b = (const float*)d_in[2];
  const float* Whh_w = (const float*)d_in[3];
  const float* Whh_b = (const float*)d_in[4];
  const float* Wph_w = (const float*)d_in[5];
  const float* Wph_b = (const float*)d_in[6];
  float* out = (float*)d_out;

  (void)hipFuncSetAttribute((const void*)rnn_fused,
                            hipFuncAttributeMaxDynamicSharedMemorySize, 132096);

  bf16* gx; bf16* gwhx; bf16* gwhhp; bf16* gwph;
  hipGetSymbolAddress((void**)&gx,    HIP_SYMBOL(g_x));
  hipGetSymbolAddress((void**)&gwhx,  HIP_SYMBOL(g_whx));
  hipGetSymbolAddress((void**)&gwhhp, HIP_SYMBOL(g_whhp));
  hipGetSymbolAddress((void**)&gwph,  HIP_SYMBOL(g_wph));

  cvt_bf16<<<BATCH * D_DIM / 2048, 256, 0, stream>>>(x,     gx,   BATCH * D_DIM);
  cvt_bf16<<<H_DIM * D_DIM / 2048, 256, 0, stream>>>(Whx_w, gwhx, H_DIM * D_DIM);
  pack_whh<<<H_DIM * H_DIM / 8 / 256, 256, 0, stream>>>(Whh_w, gwhhp);
  cvt_bf16<<<(O_DIM * H_DIM / 8 + 255) / 256, 256, 0, stream>>>(Wph_w, gwph, O_DIM * H_DIM);
  cvt_bias<<<4, 256, 0, stream>>>(Whx_b, Whh_b, Wph_b);

  // cooperative launch: 256 blocks, 1/CU co-resident (LDS-bound), grid.sync per step
  const dim3 grid(BATCH / BM), block(NTHREADS);
  const size_t lds = (size_t)BM * LSTR * sizeof(bf16);   // 132096 B
  void* args[] = { (void*)&out };
  hipLaunchCooperativeKernel((const void*)rnn_fused, grid, block, args,
                             (unsigned int)lds, stream);
}

// Round 9
// 10242.036 us; speedup vs baseline: 1.8318x; 1.7749x over previous
//
#include <hip/hip_runtime.h>

#define BATCH    16384
#define H_DIM    1024
#define D_DIM    512
#define O_DIM    10
#define SEQ      128
#define BM       64
#define NTHREADS 1024   // 16 waves; 1 block/CU; 4 waves/SIMD
#define LSTR     1032   // row stride 2064 B = 129 x 16B (odd) -> conflict-free b128 A-reads

typedef __bf16 bf16;
typedef __bf16 bf16x8 __attribute__((ext_vector_type(8)));
typedef float  f32x16 __attribute__((ext_vector_type(16)));
typedef float  f32x4  __attribute__((ext_vector_type(4)));

// ---- static device buffers ----
__device__ bf16  g_x[BATCH * D_DIM];       // 16 MB
__device__ bf16  g_whx[H_DIM * D_DIM];     // 1 MB (phase-0 only)
__device__ bf16  g_whhp[H_DIM * H_DIM];    // 2 MB wave-fragment-packed Whh (16-wave geometry)
__device__ bf16  g_wph[O_DIM * H_DIM];     // 20 KB
__device__ bf16  g_xwp[BATCH * H_DIM];     // 32 MB packed xW+bias (C-frag order)
__device__ float g_bias[H_DIM];
__device__ float g_bph[O_DIM];

__device__ __forceinline__ float fast_tanh(float z) {
  float e = __expf(2.0f * z);
  return 1.0f - 2.0f / (e + 1.0f);
}

__global__ void cvt_bf16(const float* __restrict__ src, bf16* __restrict__ dst, int n) {
  const int i = (blockIdx.x * blockDim.x + threadIdx.x) * 8;
  if (i >= n) return;
  f32x4 s0 = *(const f32x4*)(src + i);
  f32x4 s1 = *(const f32x4*)(src + i + 4);
  bf16x8 v;
  #pragma unroll
  for (int j = 0; j < 4; ++j) { v[j] = (bf16)s0[j]; v[4 + j] = (bf16)s1[j]; }
  *(bf16x8*)(dst + i) = v;
}

// pack Whh for 16 waves x 2 n-frags:
// dst[(((w*64+kc)*2+nt)*64+lane)*8+j] = Whh[w*64+nt*32+(lane&31)][kc*16+(lane>>5)*8+j]
__global__ void pack_whh(const float* __restrict__ src, bf16* __restrict__ dst) {
  const int t = blockIdx.x * blockDim.x + threadIdx.x;   // 0..131071
  const int lane = t & 63;
  const int gidx = t >> 6;               // (w*64+kc)*2+nt
  const int nt = gidx & 1, kc = (gidx >> 1) & 63, w = gidx >> 7;
  const int row = w * 64 + nt * 32 + (lane & 31);
  const int col = kc * 16 + (lane >> 5) * 8;
  const float* s = src + (size_t)row * H_DIM + col;
  bf16x8 v;
  #pragma unroll
  for (int j = 0; j < 8; ++j) v[j] = (bf16)s[j];
  *(bf16x8*)(dst + (size_t)t * 8) = v;
}

__global__ void cvt_bias(const float* __restrict__ bx, const float* __restrict__ bh,
                         const float* __restrict__ bp) {
  const int i = blockIdx.x * blockDim.x + threadIdx.x;
  if (i < H_DIM) g_bias[i] = bx[i] + bh[i];
  if (i < O_DIM) g_bph[i]  = bp[i];
}

#define MFMA4(A0, A1, B)                                                               \
  acc[0][0] = __builtin_amdgcn_mfma_f32_32x32x16_bf16(A0, (B)[0], acc[0][0], 0, 0, 0); \
  acc[0][1] = __builtin_amdgcn_mfma_f32_32x32x16_bf16(A0, (B)[1], acc[0][1], 0, 0, 0); \
  acc[1][0] = __builtin_amdgcn_mfma_f32_32x32x16_bf16(A1, (B)[0], acc[1][0], 0, 0, 0); \
  acc[1][1] = __builtin_amdgcn_mfma_f32_32x32x16_bf16(A1, (B)[1], acc[1][1], 0, 0, 0);

// 256 blocks x 1024 threads: one block/CU, 16 waves/CU (4/SIMD -> 2x TLP of r6).
// Wave tile = 64 rows x 64 cols; acc = 64 AGPR so total regs fit the 128 budget.
// h in LDS. Whh: packed per-wave streams, depth-2 register prefetch.
// xW: packed global; loads issue before __syncthreads so the barrier drain
// hides their latency. No cooperative launch (r8 failed co-residency -> no-op).
__global__ __launch_bounds__(NTHREADS, 4)
void rnn_fused(float* __restrict__ out)
{
  extern __shared__ char smem[];
  bf16* hbuf = (bf16*)smem;

  const int tid  = threadIdx.x;
  const int wave = tid >> 6;    // 0..15
  const int lane = tid & 63;
  const int m31  = lane & 31;
  const int q    = lane >> 5;
  const int r0   = blockIdx.x * BM;
  const int nw0  = wave * 64;   // this wave's 64-col slice

  const bf16* bstr  = g_whhp + (size_t)wave * (64 * 2 * 512) + lane * 8;
  bf16*       xbase = g_xwp + ((size_t)blockIdx.x * 16 + wave) * 4096 + lane * 8;

  f32x16 acc[2][2];

  // ---------------- Phase 0: xwb = x @ Whx^T + bias; h1 = tanh(xwb); xW -> global ----------------
  #pragma unroll
  for (int mt = 0; mt < 2; ++mt)
    #pragma unroll
    for (int nt = 0; nt < 2; ++nt)
      #pragma unroll
      for (int i = 0; i < 16; ++i) acc[mt][nt][i] = 0.0f;

  {
    const bf16* aBase = g_x + (size_t)(r0 + m31) * D_DIM + q * 8;
    #pragma unroll 4
    for (int kc = 0; kc < D_DIM / 16; ++kc) {
      bf16x8 a0 = *(const bf16x8*)(aBase + kc * 16);
      bf16x8 a1 = *(const bf16x8*)(aBase + (size_t)32 * D_DIM + kc * 16);
      bf16x8 b[2];
      #pragma unroll
      for (int nt = 0; nt < 2; ++nt)
        b[nt] = *(const bf16x8*)(g_whx + (size_t)(nw0 + nt * 32 + m31) * D_DIM + kc * 16 + q * 8);
      MFMA4(a0, a1, b);
    }
  }

  {
    bf16x8 xq[8];
    #pragma unroll
    for (int nt = 0; nt < 2; ++nt) {
      const int col = nw0 + nt * 32 + m31;
      const float bias = g_bias[col];
      #pragma unroll
      for (int mt = 0; mt < 2; ++mt)
        #pragma unroll
        for (int r = 0; r < 16; ++r) {
          const int row = mt * 32 + (r & 3) + 8 * (r >> 2) + 4 * q;  // C/D layout (m74/m101)
          const int idx = (nt * 2 + mt) * 16 + r;
          const float v = acc[mt][nt][r] + bias;
          xq[idx >> 3][idx & 7] = (bf16)v;
          hbuf[row * LSTR + col] = (bf16)fast_tanh(v);
        }
    }
    #pragma unroll
    for (int i = 0; i < 8; ++i) *(bf16x8*)(xbase + i * 512) = xq[i];
  }
  __syncthreads();

  // ---------------- RNN steps 2..SEQ ----------------
  const bf16* aP0 = hbuf + m31 * LSTR + q * 8;
  const bf16* aP1 = aP0 + 32 * LSTR;

  for (int step = 1; step < SEQ; ++step) {
    #pragma unroll
    for (int mt = 0; mt < 2; ++mt)
      #pragma unroll
      for (int nt = 0; nt < 2; ++nt)
        #pragma unroll
        for (int i = 0; i < 16; ++i) acc[mt][nt][i] = 0.0f;

    bf16x8 bb[2][2];
    #pragma unroll
    for (int nt = 0; nt < 2; ++nt) bb[0][nt] = *(const bf16x8*)(bstr + nt * 512);
    #pragma unroll
    for (int nt = 0; nt < 2; ++nt) bb[1][nt] = *(const bf16x8*)(bstr + (2 + nt) * 512);

    #pragma unroll
    for (int kc = 0; kc < 64; ++kc) {
      bf16x8 a0 = *(const bf16x8*)(aP0 + kc * 16);
      bf16x8 a1 = *(const bf16x8*)(aP1 + kc * 16);
      MFMA4(a0, a1, bb[kc & 1]);
      if (kc + 2 < 64) {
        #pragma unroll
        for (int nt = 0; nt < 2; ++nt)
          bb[kc & 1][nt] = *(const bf16x8*)(bstr + ((kc + 2) * 2 + nt) * 512);
      }
    }

    // xW loads issue here; barrier's vmcnt(0) drain hides their latency
    bf16x8 xq[8];
    #pragma unroll
    for (int i = 0; i < 8; ++i) xq[i] = *(const bf16x8*)(xbase + i * 512);

    __syncthreads();   // all waves done READING hbuf

    #pragma unroll
    for (int nt = 0; nt < 2; ++nt) {
      const int col = nw0 + nt * 32 + m31;
      #pragma unroll
      for (int mt = 0; mt < 2; ++mt)
        #pragma unroll
        for (int r = 0; r < 16; ++r) {
          const int row = mt * 32 + (r & 3) + 8 * (r >> 2) + 4 * q;
          const int idx = (nt * 2 + mt) * 16 + r;
          hbuf[row * LSTR + col] = (bf16)fast_tanh(acc[mt][nt][r] + (float)xq[idx >> 3][idx & 7]);
        }
    }
    __syncthreads();   // new h visible
  }

  // ---------------- Output head: softmax(h @ Wph^T + b), fp32 out ----------------
  {
    const int row  = tid >> 4;   // 0..63
    const int tsub = tid & 15;   // 16 threads per row, k-partitioned
    float p[O_DIM];
    #pragma unroll
    for (int o = 0; o < O_DIM; ++o) p[o] = 0.0f;

    const bf16* hrow = hbuf + row * LSTR;
    const int k0 = tsub * 64;
    for (int kk = 0; kk < 64; kk += 8) {
      bf16x8 hv = *(const bf16x8*)(hrow + k0 + kk);
      float hf[8];
      #pragma unroll
      for (int j = 0; j < 8; ++j) hf[j] = (float)hv[j];
      #pragma unroll
      for (int o = 0; o < O_DIM; ++o) {
        bf16x8 wv = *(const bf16x8*)(g_wph + (size_t)o * H_DIM + k0 + kk);
        #pragma unroll
        for (int j = 0; j < 8; ++j) p[o] += hf[j] * (float)wv[j];
      }
    }
    #pragma unroll
    for (int d = 1; d < 16; d <<= 1)
      #pragma unroll
      for (int o = 0; o < O_DIM; ++o) p[o] += __shfl_xor(p[o], d, 16);

    if (tsub == 0) {
      float v[O_DIM], mx = -1e30f;
      #pragma unroll
      for (int o = 0; o < O_DIM; ++o) { v[o] = p[o] + g_bph[o]; mx = fmaxf(mx, v[o]); }
      float s = 0.0f;
      #pragma unroll
      for (int o = 0; o < O_DIM; ++o) { v[o] = __expf(v[o] - mx); s += v[o]; }
      const float inv = 1.0f / s;
      #pragma unroll
      for (int o = 0; o < O_DIM; ++o)
        out[(size_t)(r0 + row) * O_DIM + o] = v[o] * inv;
    }
  }
}

extern "C" void kernel_launch(void* const* d_in, const int* in_sizes, int n_in,
                              void* d_out, int out_size, void* d_ws, size_t ws_size,
                              hipStream_t stream)
{
  (void)d_ws; (void)ws_size; (void)in_sizes; (void)n_in; (void)out_size;
  const float* x     = (const float*)d_in[0];
  const float* Whx_w = (const float*)d_in[1];
  const float* Whx_b = (const float*)d_in[2];
  const float* Whh_w = (const float*)d_in[3];
  const float* Whh_b = (const float*)d_in[4];
  const float* Wph_w = (const float*)d_in[5];
  const float* Wph_b = (const float*)d_in[6];
  float* out = (float*)d_out;

  (void)hipFuncSetAttribute((const void*)rnn_fused,
                            hipFuncAttributeMaxDynamicSharedMemorySize, 132096);

  bf16* gx; bf16* gwhx; bf16* gwhhp; bf16* gwph;
  hipGetSymbolAddress((void**)&gx,    HIP_SYMBOL(g_x));
  hipGetSymbolAddress((void**)&gwhx,  HIP_SYMBOL(g_whx));
  hipGetSymbolAddress((void**)&gwhhp, HIP_SYMBOL(g_whhp));
  hipGetSymbolAddress((void**)&gwph,  HIP_SYMBOL(g_wph));

  cvt_bf16<<<BATCH * D_DIM / 2048, 256, 0, stream>>>(x,     gx,   BATCH * D_DIM);
  cvt_bf16<<<H_DIM * D_DIM / 2048, 256, 0, stream>>>(Whx_w, gwhx, H_DIM * D_DIM);
  pack_whh<<<H_DIM * H_DIM / 8 / 256, 256, 0, stream>>>(Whh_w, gwhhp);
  cvt_bf16<<<(O_DIM * H_DIM / 8 + 255) / 256, 256, 0, stream>>>(Wph_w, gwph, O_DIM * H_DIM);
  cvt_bias<<<4, 256, 0, stream>>>(Whx_b, Whh_b, Wph_b);

  // plain launch: 256 blocks x 1024 thr, 1 block/CU, 16 waves/CU
  const dim3 grid(BATCH / BM), block(NTHREADS);
  const size_t lds = (size_t)BM * LSTR * sizeof(bf16);   // 132096 B
  rnn_fused<<<grid, block, lds, stream>>>(out);
}